// Round 8
// baseline (211.925 us; speedup 1.0000x reference)
//
#include <hip/hip_runtime.h>
#include <hip/hip_bf16.h>

// Problem constants
#define BB 4
#define TT 512
#define JJ 17
#define DD 256
#define HH 8
#define MROWS (BB*TT*JJ)            // 34816 = 272 * 128
#define SZE ((size_t)MROWS * DD)    // 8,912,896 elems
#define WSZ (DD*DD)                 // 65536
#define QSCALE 0.2550265247510319f  // 32^-0.5 * log2(e)
#define RST (17*256)                // row stride of [*, j, d] tensors (4352)

typedef short v8s __attribute__((ext_vector_type(8)));   // 8 bf16 in 4 VGPRs
typedef float v4f __attribute__((ext_vector_type(4)));   // MFMA accumulator
typedef float v16f __attribute__((ext_vector_type(16))); // 32x32 MFMA acc

// f32->bf16 round-to-nearest-even (accuracy-critical paths)
__device__ __forceinline__ unsigned short f2bf(float f) {
    union { float f; unsigned int u; } c; c.f = f;
    unsigned int u = c.u;
    return (unsigned short)((u + 0x7FFF + ((u >> 16) & 1)) >> 16);
}
// hot path: pack two f32 -> two bf16 (round-half-up), 2 add + 1 perm
__device__ __forceinline__ unsigned int pkbf(float lo, float hi) {
    union { float f; unsigned int u; } a, b; a.f = lo; b.f = hi;
    return __builtin_amdgcn_perm(b.u + 0x8000u, a.u + 0x8000u, 0x07060302u);
}
// bare v_exp_f32 (2^x); scores bounded, denorm P irrelevant to softmax sum.
__device__ __forceinline__ float fexp2(float x) {
    return __builtin_amdgcn_exp2f(x);
}

// async global->LDS, 16B per lane (HW: wave-uniform base + lane*16)
__device__ __forceinline__ void gld16(const unsigned short* g, unsigned short* l) {
    __builtin_amdgcn_global_load_lds(
        (const __attribute__((address_space(1))) void*)g,
        (__attribute__((address_space(3))) void*)l,
        16, 0, 0);
}

// ---------------------------------------------------------------------------
// Weights-only prep: fp32 -> bf16 (RNE). 128 blocks, exact cover.
// ---------------------------------------------------------------------------
__global__ __launch_bounds__(256) void prepw_kernel(
    const float* __restrict__ Wq, const float* __restrict__ Wk,
    const float* __restrict__ Wv, const float* __restrict__ Wp,
    unsigned short* __restrict__ Wqb, unsigned short* __restrict__ Wkb,
    unsigned short* __restrict__ Wvb, unsigned short* __restrict__ Wpb)
{
    size_t k = ((size_t)blockIdx.x * 256 + threadIdx.x) * 8;   // < 262144
    int w = (int)(k >> 16);         // WSZ = 65536
    size_t off = k & (WSZ - 1);
    const float* src = (w == 0) ? Wq : (w == 1) ? Wk : (w == 2) ? Wv : Wp;
    unsigned short* dst = (w == 0) ? Wqb : (w == 1) ? Wkb : (w == 2) ? Wvb : Wpb;
    float4 x0 = *(const float4*)(src + off);
    float4 x1 = *(const float4*)(src + off + 4);
    union { unsigned short s[8]; int4 v; } u;
    u.s[0] = f2bf(x0.x); u.s[1] = f2bf(x0.y);
    u.s[2] = f2bf(x0.z); u.s[3] = f2bf(x0.w);
    u.s[4] = f2bf(x1.x); u.s[5] = f2bf(x1.y);
    u.s[6] = f2bf(x1.z); u.s[7] = f2bf(x1.w);
    *(int4*)(dst + off) = u.v;
}

// ---------------------------------------------------------------------------
// QKV GEMM with fused fp32->bf16 A-conversion (unchanged from R7).
// ---------------------------------------------------------------------------
__global__ __launch_bounds__(512) void gemm_kernel(
    const float* __restrict__ Aq,    // q fp32   (z==0)
    const float* __restrict__ Akv,   // kv fp32  (z==1,2)
    const unsigned short* __restrict__ W0,
    const unsigned short* __restrict__ W1,
    const unsigned short* __restrict__ W2,
    unsigned short* __restrict__ Y0,
    unsigned short* __restrict__ Y1,
    unsigned short* __restrict__ Y2)
{
    const int z = blockIdx.y;
    const float* A          = (z == 0) ? Aq : Akv;
    const float ascale      = (z == 0) ? QSCALE : 1.f;
    const unsigned short* W = (z == 0) ? W0 : (z == 1) ? W1 : W2;
    unsigned short* Y       = (z == 0) ? Y0 : (z == 1) ? Y1 : Y2;

    const int bm = blockIdx.x;   // 272 M-tiles

    __shared__ unsigned short As[2][128 * 32];   // 8 KB x2, linear
    __shared__ unsigned short Bs[2][256 * 32];   // 16 KB x2, linear

    const int tid  = threadIdx.x;
    const int wv   = tid >> 6;     // 0..7
    const int lane = tid & 63;
    const int wm   = wv & 1;       // M half (64 rows)
    const int wn   = wv >> 1;      // N quarter (64 cols)
    const int quad = lane >> 4;
    const int l16  = lane & 15;

    // --- staging geometry (source pre-swizzle; LDS dest linear) ---
    const int srow  = tid >> 2;             // 0..127
    const int chunk = tid & 3;              // 16B chunk within 64B LDS row
    const int s4    = srow & 15;
    const int cg    = chunk ^ ((s4 ^ (s4 >> 2)) & 3);   // swizzled src chunk
    const float* gA = A + (size_t)(bm * 128 + srow) * 256 + cg * 8;  // fp32!
    const unsigned short* gB0 = W + (size_t)srow * 256 + cg * 8;
    const unsigned short* gB1 = W + (size_t)(128 + srow) * 256 + cg * 8;
    unsigned short* lA  = &As[0][tid * 8];         // == srow*32 + chunk*8
    unsigned short* lB0 = &Bs[0][tid * 8];
    unsigned short* lB1 = &Bs[0][4096 + tid * 8];

    // --- read-side swizzle (same involution; row&15 == l16) ---
    const int rch8 = (quad ^ ((l16 ^ (l16 >> 2)) & 3)) * 8;

    v4f acc[4][4] = {};

    // prologue: stage tile 0
    {
        float4 a0 = *(const float4*)(gA);
        float4 a1 = *(const float4*)(gA + 4);
        union { unsigned short s[8]; int4 v; } ua;
        ua.s[0] = f2bf(a0.x * ascale); ua.s[1] = f2bf(a0.y * ascale);
        ua.s[2] = f2bf(a0.z * ascale); ua.s[3] = f2bf(a0.w * ascale);
        ua.s[4] = f2bf(a1.x * ascale); ua.s[5] = f2bf(a1.y * ascale);
        ua.s[6] = f2bf(a1.z * ascale); ua.s[7] = f2bf(a1.w * ascale);
        *(int4*)(lA) = ua.v;
    }
    gld16(gB0, lB0);
    gld16(gB1, lB1);
    __syncthreads();

    for (int kt = 0; kt < 8; ++kt) {
        const int cur = kt & 1;
        const int nb  = cur ^ 1;
        float4 a0, a1;
        if (kt < 7) {               // issue next-tile loads (latency hides
            const int nk = (kt + 1) * 32;   // under the MFMA phase below)
            a0 = *(const float4*)(gA + nk);
            a1 = *(const float4*)(gA + nk + 4);
            gld16(gB0 + nk, lB0 + nb * 8192);
            gld16(gB1 + nk, lB1 + nb * 8192);
        }
        v8s a[4], b[4];
        #pragma unroll
        for (int i = 0; i < 4; ++i)
            a[i] = *(const v8s*)(&As[cur][(wm * 64 + i * 16 + l16) * 32 + rch8]);
        #pragma unroll
        for (int j = 0; j < 4; ++j)
            b[j] = *(const v8s*)(&Bs[cur][(wn * 64 + j * 16 + l16) * 32 + rch8]);
        #pragma unroll
        for (int i = 0; i < 4; ++i)
            #pragma unroll
            for (int j = 0; j < 4; ++j)
                acc[i][j] = __builtin_amdgcn_mfma_f32_16x16x32_bf16(
                    a[i], b[j], acc[i][j], 0, 0, 0);
        if (kt < 7) {               // cvt + write A-next (same kt body)
            union { unsigned short s[8]; int4 v; } ua;
            ua.s[0] = f2bf(a0.x * ascale); ua.s[1] = f2bf(a0.y * ascale);
            ua.s[2] = f2bf(a0.z * ascale); ua.s[3] = f2bf(a0.w * ascale);
            ua.s[4] = f2bf(a1.x * ascale); ua.s[5] = f2bf(a1.y * ascale);
            ua.s[6] = f2bf(a1.z * ascale); ua.s[7] = f2bf(a1.w * ascale);
            *(int4*)(lA + nb * 4096) = ua.v;
        }
        __syncthreads();   // drains gld16 (vmcnt) + ds ops (lgkm)
    }

    #pragma unroll
    for (int i = 0; i < 4; ++i)
        #pragma unroll
        for (int j = 0; j < 4; ++j)
            #pragma unroll
            for (int r = 0; r < 4; ++r) {
                int gm = bm * 128 + wm * 64 + i * 16 + quad * 4 + r;
                int gn = wn * 64 + j * 16 + l16;
                Y[(size_t)gm * 256 + gn] = f2bf(acc[i][j][r]);
            }
}

// ---------------------------------------------------------------------------
// Output GEMM (unchanged from R7).
// ---------------------------------------------------------------------------
__global__ __launch_bounds__(256) void gemmo_kernel(
    const unsigned short* __restrict__ A,
    const unsigned short* __restrict__ W,
    const float* __restrict__ bias,
    float* __restrict__ out)
{
    const int bm = blockIdx.x;   // 544 tiles of 64 rows

    __shared__ unsigned short As[2][64 * 32];    // 4 KB x2
    __shared__ unsigned short Bs[2][256 * 32];   // 16 KB x2

    const int tid  = threadIdx.x;
    const int lane = tid & 63;
    const int wn   = tid >> 6;     // N quarter
    const int quad = lane >> 4;
    const int l16  = lane & 15;

    const int arow  = tid >> 2;               // 0..63
    const int chunk = tid & 3;
    const int cgA   = (chunk ^ ((arow ^ (arow >> 2)) & 3)) * 8;
    const unsigned short* gA = A + (size_t)(bm * 64 + arow) * 256 + cgA;
    const unsigned short* gB = W + (size_t)arow * 256 + cgA;   // + p*64 rows
    unsigned short* lA = &As[0][tid * 8];
    unsigned short* lB = &Bs[0][tid * 8];

    const int rch8 = (quad ^ ((l16 ^ (l16 >> 2)) & 3)) * 8;

    v4f acc[4][4] = {};

    gld16(gA, lA);
    #pragma unroll
    for (int p = 0; p < 4; ++p)
        gld16(gB + (size_t)p * 64 * 256, lB + p * 2048);
    __syncthreads();

    for (int kt = 0; kt < 8; ++kt) {
        const int cur = kt & 1;
        if (kt < 7) {
            const int nk = (kt + 1) * 32;
            const int nb = cur ^ 1;
            gld16(gA + nk, lA + nb * 2048);
            #pragma unroll
            for (int p = 0; p < 4; ++p)
                gld16(gB + (size_t)p * 64 * 256 + nk, lB + nb * 8192 + p * 2048);
        }
        v8s a[4], b[4];
        #pragma unroll
        for (int i = 0; i < 4; ++i)
            a[i] = *(const v8s*)(&As[cur][(i * 16 + l16) * 32 + rch8]);
        #pragma unroll
        for (int j = 0; j < 4; ++j)
            b[j] = *(const v8s*)(&Bs[cur][(wn * 64 + j * 16 + l16) * 32 + rch8]);
        #pragma unroll
        for (int i = 0; i < 4; ++i)
            #pragma unroll
            for (int j = 0; j < 4; ++j)
                acc[i][j] = __builtin_amdgcn_mfma_f32_16x16x32_bf16(
                    a[i], b[j], acc[i][j], 0, 0, 0);
        __syncthreads();
    }

    #pragma unroll
    for (int i = 0; i < 4; ++i)
        #pragma unroll
        for (int j = 0; j < 4; ++j)
            #pragma unroll
            for (int r = 0; r < 4; ++r) {
                int gm = bm * 64 + i * 16 + quad * 4 + r;
                int gn = wn * 64 + j * 16 + l16;
                out[(size_t)gm * 256 + gn] = acc[i][j][r] + bias[gn];
            }
}

// ---------------------------------------------------------------------------
// Fused attention, R8: Ps ELIMINATED. PV switched to mfma_32x32x16 whose
// A-fragment (row=(lane&31): both fi at once; k=(lane>>5)*8+i) is reachable
// from the 16x16 ST output layout with ONE __shfl_xor(.,16) per dword:
// each lane keeps its own-fi packed dwords and receives its partner's
// (lane^16) opposite-fi dwords. LDS 37.9->19.4 KB and launch_bounds(256,8)
// (VGPR<=64) -> 8 blocks/CU (2x occupancy). Per-half lgkm drain gone.
// Per-si structure: ST pair -> softmax -> pack+shuffle -> PV (accST
// liveness 32->8 regs). K/V staging, XCD grid, fexp2 unchanged (proven).
// ---------------------------------------------------------------------------
#define VST 136   // Vs stride (16B-aligned rows), XOR-swizzled s-blocks

__global__ __launch_bounds__(256, 8) void attn_kernel(
    const unsigned short* __restrict__ Qp,
    const unsigned short* __restrict__ Kp,
    const unsigned short* __restrict__ Vp,
    unsigned short* __restrict__ Att)
{
    // XCD-grouped id mapping (proven: -68MB FETCH)
    const int id  = blockIdx.x;            // 0..2175
    const int bjh = (id & 7) | ((id >> 5) << 3);   // 0..543
    const int qt  = (id >> 3) & 3;
    const int h   = bjh & 7;
    const int bj  = bjh >> 3;
    const int j   = bj % 17;
    const int b_  = bj / 17;

    __shared__ unsigned short Ks[128 * 40];    // [s][cd], pad 40  (10.25 KB)
    __shared__ unsigned short Vs[32 * VST];    // [cd][s], swizzled (8.7 KB)
    __shared__ float Ls[128];                  // row sums          (0.5 KB)

    const int tid  = threadIdx.x;
    const int wave = tid >> 6;
    const int lane = tid & 63;
    const int quad = lane >> 4;
    const int l16  = lane & 15;
    const int qo   = quad & 1;    // fi of this lane's PV rows
    const int q2   = quad >> 1;   // k-half selector

    const int base0 = b_ * 512 * RST + j * 256 + h * 32;

    // Q fragments straight from global
    v8s qa[2];
    #pragma unroll
    for (int fi = 0; fi < 2; ++fi)
        qa[fi] = *(const v8s*)(
            Qp + base0 + (qt * 128 + wave * 32 + fi * 16 + l16) * RST + quad * 8);

    float lacc[2] = {0.f, 0.f};
    v16f accO = {};   // 32x32 C/D: col=lane&31=cd, row=(r&3)+8*(r>>2)+4*q2

    for (int kc = 0; kc < 4; ++kc) {
        __syncthreads();   // protect previous-iteration Ks/Vs reads
        // stage K chunk [128][32], conflict-free writer mapping
        #pragma unroll
        for (int c = 0; c < 2; ++c) {
            int krow = wave * 16 + l16 + c * 64;
            *(int4*)(&Ks[krow * 40 + quad * 8]) = *(const int4*)(
                Kp + base0 + (kc * 128 + krow) * RST + quad * 8);
        }
        // stage V chunk transposed with XOR swizzle (static scatter)
        #pragma unroll
        for (int c = 0; c < 2; ++c) {
            int idx  = c * 256 + tid;
            int srow = idx >> 2;
            int cd0  = (idx & 3) << 3;
            int xof  = (((srow >> 3) ^ (cd0 >> 3)) << 3) + (srow & 7);
            union { int4 v; unsigned short s[8]; } u;
            u.v = *(const int4*)(
                Vp + base0 + (kc * 128 + srow) * RST + cd0);
            #pragma unroll
            for (int i = 0; i < 8; ++i)
                Vs[(cd0 + i) * VST + xof] = u.s[i];
        }
        __syncthreads();

        #pragma unroll
        for (int half = 0; half < 2; ++half) {
            #pragma unroll
            for (int si = 0; si < 4; ++si) {
                // S^T = K @ Q^T, one 16-s slice; col=qrow(l16), row=s
                v8s kb = *(const v8s*)(&Ks[((half * 4 + si) * 16 + l16) * 40 + quad * 8]);
                v4f st0 = {}, st1 = {};
                __builtin_amdgcn_s_setprio(1);
                st0 = __builtin_amdgcn_mfma_f32_16x16x32_bf16(kb, qa[0], st0, 0, 0, 0);
                st1 = __builtin_amdgcn_mfma_f32_16x16x32_bf16(kb, qa[1], st1, 0, 0, 0);
                __builtin_amdgcn_s_setprio(0);
                // softmax (log2 domain, no max-sub) + row-sum partials
                float p00 = fexp2(st0[0]), p01 = fexp2(st0[1]);
                float p02 = fexp2(st0[2]), p03 = fexp2(st0[3]);
                float p10 = fexp2(st1[0]), p11 = fexp2(st1[1]);
                float p12 = fexp2(st1[2]), p13 = fexp2(st1[3]);
                lacc[0] += (p00 + p01) + (p02 + p03);
                lacc[1] += (p10 + p11) + (p12 + p13);
                // pack: D[fi][w], own s-range = quad*4 (== q2*8 + qo*4)
                unsigned int D00 = pkbf(p00, p01), D01 = pkbf(p02, p03);
                unsigned int D10 = pkbf(p10, p11), D11 = pkbf(p12, p13);
                // exchange with partner lane^16: send opposite-fi dwords
                unsigned int P0 = qo ? D00 : D10;
                unsigned int P1 = qo ? D01 : D11;
                unsigned int S0 = __shfl_xor(P0, 16);
                unsigned int S1 = __shfl_xor(P1, 16);
                // assemble 32x32 A-frag: row=qo*16+l16, k=q2*8+i, s=si*16+k
                union { unsigned int u[4]; v8s v; } pa;
                pa.u[0] = qo ? S0 : D00;
                pa.u[1] = qo ? S1 : D01;
                pa.u[2] = qo ? D10 : S0;
                pa.u[3] = qo ? D11 : S1;
                // V B-frag: col=cd=qo*16+l16, k=q2*8+i -> 8 consecutive s
                int cd   = qo * 16 + l16;
                int sblk = half * 8 + si * 2 + q2;
                v8s vb = *(const v8s*)(&Vs[cd * VST + ((sblk ^ (cd >> 3)) << 3)]);
                __builtin_amdgcn_s_setprio(1);
                accO = __builtin_amdgcn_mfma_f32_32x32x16_bf16(pa.v, vb, accO, 0, 0, 0);
                __builtin_amdgcn_s_setprio(0);
            }
        }
    }

    // final l: reduce lane partials across the 4 quads sharing each qrow
    #pragma unroll
    for (int fi = 0; fi < 2; ++fi) {
        float lv = lacc[fi];
        lv += __shfl_xor(lv, 16);
        lv += __shfl_xor(lv, 32);
        if (quad == 0) Ls[wave * 32 + fi * 16 + l16] = lv;
    }
    asm volatile("s_waitcnt lgkmcnt(0)" ::: "memory");   // wave-private rows

    // epilogue: 32x32 C/D -> Att row-major [(b,t,j)][(h,cd)]
    const int cdo = qo * 16 + l16;
    #pragma unroll
    for (int g = 0; g < 4; ++g) {
        float4 lv = *(float4*)(&Ls[wave * 32 + g * 8 + q2 * 4]);
        float rl[4] = {1.f / lv.x, 1.f / lv.y, 1.f / lv.z, 1.f / lv.w};
        #pragma unroll
        for (int r = 0; r < 4; ++r) {
            int qrow = g * 8 + q2 * 4 + r;
            int trow = qt * 128 + wave * 32 + qrow;
            float v  = accO[g * 4 + r] * rl[r];
            Att[(size_t)(base0 + trow * RST + cdo)] = f2bf(v);
        }
    }
}

extern "C" void kernel_launch(void* const* d_in, const int* in_sizes, int n_in,
                              void* d_out, int out_size, void* d_ws, size_t ws_size,
                              hipStream_t stream) {
    const float* q  = (const float*)d_in[0];
    const float* kv = (const float*)d_in[1];
    const float* Wq = (const float*)d_in[2];
    const float* Wk = (const float*)d_in[3];
    const float* Wv = (const float*)d_in[4];
    const float* Wp = (const float*)d_in[5];
    const float* bp = (const float*)d_in[6];

    unsigned short* ws  = (unsigned short*)d_ws;
    unsigned short* Qp  = ws;                 // SZE
    unsigned short* Kp  = ws + SZE;           // SZE
    unsigned short* Vp  = ws + 2 * SZE;       // SZE
    unsigned short* Att = ws + 3 * SZE;       // SZE
    unsigned short* Wqb = ws + 4 * SZE;
    unsigned short* Wkb = Wqb + WSZ;
    unsigned short* Wvb = Wkb + WSZ;
    unsigned short* Wpb = Wvb + WSZ;
    float* out = (float*)d_out;

    // 0) weights-only fp32 -> bf16 prep
    prepw_kernel<<<128, 256, 0, stream>>>(Wq, Wk, Wv, Wp,
                                          Wqb, Wkb, Wvb, Wpb);
    // 1) Q/K/V projections: fp32 A inputs, fused conversion (QSCALE on z=0)
    gemm_kernel<<<dim3(272, 3), 512, 0, stream>>>(
        q, kv, Wqb, Wkb, Wvb, Qp, Kp, Vp);
    // 2) fused attention (XCD-grouped flat grid)
    attn_kernel<<<dim3(2176), 256, 0, stream>>>(Qp, Kp, Vp, Att);
    // 3) output projection + bias (fp32 out), BM=64 tail-friendly grid
    gemmo_kernel<<<dim3(544), 256, 0, stream>>>(Att, Wpb, bp, out);
}

// Round 9
// 198.634 us; speedup vs baseline: 1.0669x; 1.0669x over previous
//
#include <hip/hip_runtime.h>
#include <hip/hip_bf16.h>

// Problem constants
#define BB 4
#define TT 512
#define JJ 17
#define DD 256
#define HH 8
#define MROWS (BB*TT*JJ)            // 34816 = 272 * 128
#define SZE ((size_t)MROWS * DD)    // 8,912,896 elems
#define WSZ (DD*DD)                 // 65536
#define QSCALE 0.2550265247510319f  // 32^-0.5 * log2(e)
#define RST (17*256)                // row stride of [*, j, d] tensors (4352)

typedef short v8s __attribute__((ext_vector_type(8)));   // 8 bf16 in 4 VGPRs
typedef float v4f __attribute__((ext_vector_type(4)));   // MFMA accumulator
typedef float v16f __attribute__((ext_vector_type(16))); // 32x32 MFMA acc

// f32->bf16 round-to-nearest-even (accuracy-critical paths)
__device__ __forceinline__ unsigned short f2bf(float f) {
    union { float f; unsigned int u; } c; c.f = f;
    unsigned int u = c.u;
    return (unsigned short)((u + 0x7FFF + ((u >> 16) & 1)) >> 16);
}
// hot path: pack two f32 -> two bf16 (round-half-up), 2 add + 1 perm
__device__ __forceinline__ unsigned int pkbf(float lo, float hi) {
    union { float f; unsigned int u; } a, b; a.f = lo; b.f = hi;
    return __builtin_amdgcn_perm(b.u + 0x8000u, a.u + 0x8000u, 0x07060302u);
}
// bare v_exp_f32 (2^x); scores bounded, denorm P irrelevant to softmax sum.
__device__ __forceinline__ float fexp2(float x) {
    return __builtin_amdgcn_exp2f(x);
}

// async global->LDS, 16B per lane (HW: wave-uniform base + lane*16)
__device__ __forceinline__ void gld16(const unsigned short* g, unsigned short* l) {
    __builtin_amdgcn_global_load_lds(
        (const __attribute__((address_space(1))) void*)g,
        (__attribute__((address_space(3))) void*)l,
        16, 0, 0);
}

// ---------------------------------------------------------------------------
// Weights-only prep: fp32 -> bf16 (RNE). 128 blocks, exact cover.
// ---------------------------------------------------------------------------
__global__ __launch_bounds__(256) void prepw_kernel(
    const float* __restrict__ Wq, const float* __restrict__ Wk,
    const float* __restrict__ Wv, const float* __restrict__ Wp,
    unsigned short* __restrict__ Wqb, unsigned short* __restrict__ Wkb,
    unsigned short* __restrict__ Wvb, unsigned short* __restrict__ Wpb)
{
    size_t k = ((size_t)blockIdx.x * 256 + threadIdx.x) * 8;   // < 262144
    int w = (int)(k >> 16);         // WSZ = 65536
    size_t off = k & (WSZ - 1);
    const float* src = (w == 0) ? Wq : (w == 1) ? Wk : (w == 2) ? Wv : Wp;
    unsigned short* dst = (w == 0) ? Wqb : (w == 1) ? Wkb : (w == 2) ? Wvb : Wpb;
    float4 x0 = *(const float4*)(src + off);
    float4 x1 = *(const float4*)(src + off + 4);
    union { unsigned short s[8]; int4 v; } u;
    u.s[0] = f2bf(x0.x); u.s[1] = f2bf(x0.y);
    u.s[2] = f2bf(x0.z); u.s[3] = f2bf(x0.w);
    u.s[4] = f2bf(x1.x); u.s[5] = f2bf(x1.y);
    u.s[6] = f2bf(x1.z); u.s[7] = f2bf(x1.w);
    *(int4*)(dst + off) = u.v;
}

// ---------------------------------------------------------------------------
// QKV GEMM with fused fp32->bf16 A-conversion (unchanged from R7).
// ---------------------------------------------------------------------------
__global__ __launch_bounds__(512) void gemm_kernel(
    const float* __restrict__ Aq,    // q fp32   (z==0)
    const float* __restrict__ Akv,   // kv fp32  (z==1,2)
    const unsigned short* __restrict__ W0,
    const unsigned short* __restrict__ W1,
    const unsigned short* __restrict__ W2,
    unsigned short* __restrict__ Y0,
    unsigned short* __restrict__ Y1,
    unsigned short* __restrict__ Y2)
{
    const int z = blockIdx.y;
    const float* A          = (z == 0) ? Aq : Akv;
    const float ascale      = (z == 0) ? QSCALE : 1.f;
    const unsigned short* W = (z == 0) ? W0 : (z == 1) ? W1 : W2;
    unsigned short* Y       = (z == 0) ? Y0 : (z == 1) ? Y1 : Y2;

    const int bm = blockIdx.x;   // 272 M-tiles

    __shared__ unsigned short As[2][128 * 32];   // 8 KB x2, linear
    __shared__ unsigned short Bs[2][256 * 32];   // 16 KB x2, linear

    const int tid  = threadIdx.x;
    const int wv   = tid >> 6;     // 0..7
    const int lane = tid & 63;
    const int wm   = wv & 1;       // M half (64 rows)
    const int wn   = wv >> 1;      // N quarter (64 cols)
    const int quad = lane >> 4;
    const int l16  = lane & 15;

    // --- staging geometry (source pre-swizzle; LDS dest linear) ---
    const int srow  = tid >> 2;             // 0..127
    const int chunk = tid & 3;              // 16B chunk within 64B LDS row
    const int s4    = srow & 15;
    const int cg    = chunk ^ ((s4 ^ (s4 >> 2)) & 3);   // swizzled src chunk
    const float* gA = A + (size_t)(bm * 128 + srow) * 256 + cg * 8;  // fp32!
    const unsigned short* gB0 = W + (size_t)srow * 256 + cg * 8;
    const unsigned short* gB1 = W + (size_t)(128 + srow) * 256 + cg * 8;
    unsigned short* lA  = &As[0][tid * 8];         // == srow*32 + chunk*8
    unsigned short* lB0 = &Bs[0][tid * 8];
    unsigned short* lB1 = &Bs[0][4096 + tid * 8];

    // --- read-side swizzle (same involution; row&15 == l16) ---
    const int rch8 = (quad ^ ((l16 ^ (l16 >> 2)) & 3)) * 8;

    v4f acc[4][4] = {};

    // prologue: stage tile 0
    {
        float4 a0 = *(const float4*)(gA);
        float4 a1 = *(const float4*)(gA + 4);
        union { unsigned short s[8]; int4 v; } ua;
        ua.s[0] = f2bf(a0.x * ascale); ua.s[1] = f2bf(a0.y * ascale);
        ua.s[2] = f2bf(a0.z * ascale); ua.s[3] = f2bf(a0.w * ascale);
        ua.s[4] = f2bf(a1.x * ascale); ua.s[5] = f2bf(a1.y * ascale);
        ua.s[6] = f2bf(a1.z * ascale); ua.s[7] = f2bf(a1.w * ascale);
        *(int4*)(lA) = ua.v;
    }
    gld16(gB0, lB0);
    gld16(gB1, lB1);
    __syncthreads();

    for (int kt = 0; kt < 8; ++kt) {
        const int cur = kt & 1;
        const int nb  = cur ^ 1;
        float4 a0, a1;
        if (kt < 7) {               // issue next-tile loads (latency hides
            const int nk = (kt + 1) * 32;   // under the MFMA phase below)
            a0 = *(const float4*)(gA + nk);
            a1 = *(const float4*)(gA + nk + 4);
            gld16(gB0 + nk, lB0 + nb * 8192);
            gld16(gB1 + nk, lB1 + nb * 8192);
        }
        v8s a[4], b[4];
        #pragma unroll
        for (int i = 0; i < 4; ++i)
            a[i] = *(const v8s*)(&As[cur][(wm * 64 + i * 16 + l16) * 32 + rch8]);
        #pragma unroll
        for (int j = 0; j < 4; ++j)
            b[j] = *(const v8s*)(&Bs[cur][(wn * 64 + j * 16 + l16) * 32 + rch8]);
        #pragma unroll
        for (int i = 0; i < 4; ++i)
            #pragma unroll
            for (int j = 0; j < 4; ++j)
                acc[i][j] = __builtin_amdgcn_mfma_f32_16x16x32_bf16(
                    a[i], b[j], acc[i][j], 0, 0, 0);
        if (kt < 7) {               // cvt + write A-next (same kt body)
            union { unsigned short s[8]; int4 v; } ua;
            ua.s[0] = f2bf(a0.x * ascale); ua.s[1] = f2bf(a0.y * ascale);
            ua.s[2] = f2bf(a0.z * ascale); ua.s[3] = f2bf(a0.w * ascale);
            ua.s[4] = f2bf(a1.x * ascale); ua.s[5] = f2bf(a1.y * ascale);
            ua.s[6] = f2bf(a1.z * ascale); ua.s[7] = f2bf(a1.w * ascale);
            *(int4*)(lA + nb * 4096) = ua.v;
        }
        __syncthreads();   // drains gld16 (vmcnt) + ds ops (lgkm)
    }

    #pragma unroll
    for (int i = 0; i < 4; ++i)
        #pragma unroll
        for (int j = 0; j < 4; ++j)
            #pragma unroll
            for (int r = 0; r < 4; ++r) {
                int gm = bm * 128 + wm * 64 + i * 16 + quad * 4 + r;
                int gn = wn * 64 + j * 16 + l16;
                Y[(size_t)gm * 256 + gn] = f2bf(acc[i][j][r]);
            }
}

// ---------------------------------------------------------------------------
// Output GEMM (unchanged from R7).
// ---------------------------------------------------------------------------
__global__ __launch_bounds__(256) void gemmo_kernel(
    const unsigned short* __restrict__ A,
    const unsigned short* __restrict__ W,
    const float* __restrict__ bias,
    float* __restrict__ out)
{
    const int bm = blockIdx.x;   // 544 tiles of 64 rows

    __shared__ unsigned short As[2][64 * 32];    // 4 KB x2
    __shared__ unsigned short Bs[2][256 * 32];   // 16 KB x2

    const int tid  = threadIdx.x;
    const int lane = tid & 63;
    const int wn   = tid >> 6;     // N quarter
    const int quad = lane >> 4;
    const int l16  = lane & 15;

    const int arow  = tid >> 2;               // 0..63
    const int chunk = tid & 3;
    const int cgA   = (chunk ^ ((arow ^ (arow >> 2)) & 3)) * 8;
    const unsigned short* gA = A + (size_t)(bm * 64 + arow) * 256 + cgA;
    const unsigned short* gB = W + (size_t)arow * 256 + cgA;   // + p*64 rows
    unsigned short* lA = &As[0][tid * 8];
    unsigned short* lB = &Bs[0][tid * 8];

    const int rch8 = (quad ^ ((l16 ^ (l16 >> 2)) & 3)) * 8;

    v4f acc[4][4] = {};

    gld16(gA, lA);
    #pragma unroll
    for (int p = 0; p < 4; ++p)
        gld16(gB + (size_t)p * 64 * 256, lB + p * 2048);
    __syncthreads();

    for (int kt = 0; kt < 8; ++kt) {
        const int cur = kt & 1;
        if (kt < 7) {
            const int nk = (kt + 1) * 32;
            const int nb = cur ^ 1;
            gld16(gA + nk, lA + nb * 2048);
            #pragma unroll
            for (int p = 0; p < 4; ++p)
                gld16(gB + (size_t)p * 64 * 256 + nk, lB + nb * 8192 + p * 2048);
        }
        v8s a[4], b[4];
        #pragma unroll
        for (int i = 0; i < 4; ++i)
            a[i] = *(const v8s*)(&As[cur][(i * 16 + l16) * 32 + rch8]);
        #pragma unroll
        for (int j = 0; j < 4; ++j)
            b[j] = *(const v8s*)(&Bs[cur][(wn * 64 + j * 16 + l16) * 32 + rch8]);
        #pragma unroll
        for (int i = 0; i < 4; ++i)
            #pragma unroll
            for (int j = 0; j < 4; ++j)
                acc[i][j] = __builtin_amdgcn_mfma_f32_16x16x32_bf16(
                    a[i], b[j], acc[i][j], 0, 0, 0);
        __syncthreads();
    }

    #pragma unroll
    for (int i = 0; i < 4; ++i)
        #pragma unroll
        for (int j = 0; j < 4; ++j)
            #pragma unroll
            for (int r = 0; r < 4; ++r) {
                int gm = bm * 64 + i * 16 + quad * 4 + r;
                int gn = wn * 64 + j * 16 + l16;
                out[(size_t)gm * 256 + gn] = acc[i][j][r] + bias[gn];
            }
}

// ---------------------------------------------------------------------------
// Fused attention, R9: R8's Ps-free structure (PV via mfma_32x32x16 with
// one __shfl_xor(.,16)/dword; LDS 19.4KB; bank conflicts halved to 2.2M)
// with launch_bounds relaxed (256,8)->(256,4). R8's (256,8) forced a 64-reg
// unified budget -> VGPR_Count 32 + scratch spill (+47MB FETCH/WRITE, +6us).
// 128-reg budget removes the spill and keeps every structural win.
// ---------------------------------------------------------------------------
#define VST 136   // Vs stride (16B-aligned rows), XOR-swizzled s-blocks

__global__ __launch_bounds__(256, 4) void attn_kernel(
    const unsigned short* __restrict__ Qp,
    const unsigned short* __restrict__ Kp,
    const unsigned short* __restrict__ Vp,
    unsigned short* __restrict__ Att)
{
    // XCD-grouped id mapping (proven: -68MB FETCH)
    const int id  = blockIdx.x;            // 0..2175
    const int bjh = (id & 7) | ((id >> 5) << 3);   // 0..543
    const int qt  = (id >> 3) & 3;
    const int h   = bjh & 7;
    const int bj  = bjh >> 3;
    const int j   = bj % 17;
    const int b_  = bj / 17;

    __shared__ unsigned short Ks[128 * 40];    // [s][cd], pad 40  (10.25 KB)
    __shared__ unsigned short Vs[32 * VST];    // [cd][s], swizzled (8.7 KB)
    __shared__ float Ls[128];                  // row sums          (0.5 KB)

    const int tid  = threadIdx.x;
    const int wave = tid >> 6;
    const int lane = tid & 63;
    const int quad = lane >> 4;
    const int l16  = lane & 15;
    const int qo   = quad & 1;    // fi of this lane's PV rows
    const int q2   = quad >> 1;   // k-half selector

    const int base0 = b_ * 512 * RST + j * 256 + h * 32;

    // Q fragments straight from global
    v8s qa[2];
    #pragma unroll
    for (int fi = 0; fi < 2; ++fi)
        qa[fi] = *(const v8s*)(
            Qp + base0 + (qt * 128 + wave * 32 + fi * 16 + l16) * RST + quad * 8);

    float lacc[2] = {0.f, 0.f};
    v16f accO = {};   // 32x32 C/D: col=lane&31=cd, row=(r&3)+8*(r>>2)+4*q2

    for (int kc = 0; kc < 4; ++kc) {
        __syncthreads();   // protect previous-iteration Ks/Vs reads
        // stage K chunk [128][32], conflict-free writer mapping
        #pragma unroll
        for (int c = 0; c < 2; ++c) {
            int krow = wave * 16 + l16 + c * 64;
            *(int4*)(&Ks[krow * 40 + quad * 8]) = *(const int4*)(
                Kp + base0 + (kc * 128 + krow) * RST + quad * 8);
        }
        // stage V chunk transposed with XOR swizzle (static scatter)
        #pragma unroll
        for (int c = 0; c < 2; ++c) {
            int idx  = c * 256 + tid;
            int srow = idx >> 2;
            int cd0  = (idx & 3) << 3;
            int xof  = (((srow >> 3) ^ (cd0 >> 3)) << 3) + (srow & 7);
            union { int4 v; unsigned short s[8]; } u;
            u.v = *(const int4*)(
                Vp + base0 + (kc * 128 + srow) * RST + cd0);
            #pragma unroll
            for (int i = 0; i < 8; ++i)
                Vs[(cd0 + i) * VST + xof] = u.s[i];
        }
        __syncthreads();

        #pragma unroll
        for (int half = 0; half < 2; ++half) {
            #pragma unroll
            for (int si = 0; si < 4; ++si) {
                // S^T = K @ Q^T, one 16-s slice; col=qrow(l16), row=s
                v8s kb = *(const v8s*)(&Ks[((half * 4 + si) * 16 + l16) * 40 + quad * 8]);
                v4f st0 = {}, st1 = {};
                __builtin_amdgcn_s_setprio(1);
                st0 = __builtin_amdgcn_mfma_f32_16x16x32_bf16(kb, qa[0], st0, 0, 0, 0);
                st1 = __builtin_amdgcn_mfma_f32_16x16x32_bf16(kb, qa[1], st1, 0, 0, 0);
                __builtin_amdgcn_s_setprio(0);
                // softmax (log2 domain, no max-sub) + row-sum partials
                float p00 = fexp2(st0[0]), p01 = fexp2(st0[1]);
                float p02 = fexp2(st0[2]), p03 = fexp2(st0[3]);
                float p10 = fexp2(st1[0]), p11 = fexp2(st1[1]);
                float p12 = fexp2(st1[2]), p13 = fexp2(st1[3]);
                lacc[0] += (p00 + p01) + (p02 + p03);
                lacc[1] += (p10 + p11) + (p12 + p13);
                // pack: D[fi][w], own s-range = quad*4 (== q2*8 + qo*4)
                unsigned int D00 = pkbf(p00, p01), D01 = pkbf(p02, p03);
                unsigned int D10 = pkbf(p10, p11), D11 = pkbf(p12, p13);
                // exchange with partner lane^16: send opposite-fi dwords
                unsigned int P0 = qo ? D00 : D10;
                unsigned int P1 = qo ? D01 : D11;
                unsigned int S0 = __shfl_xor(P0, 16);
                unsigned int S1 = __shfl_xor(P1, 16);
                // assemble 32x32 A-frag: row=qo*16+l16, k=q2*8+i, s=si*16+k
                union { unsigned int u[4]; v8s v; } pa;
                pa.u[0] = qo ? S0 : D00;
                pa.u[1] = qo ? S1 : D01;
                pa.u[2] = qo ? D10 : S0;
                pa.u[3] = qo ? D11 : S1;
                // V B-frag: col=cd=qo*16+l16, k=q2*8+i -> 8 consecutive s
                int cd   = qo * 16 + l16;
                int sblk = half * 8 + si * 2 + q2;
                v8s vb = *(const v8s*)(&Vs[cd * VST + ((sblk ^ (cd >> 3)) << 3)]);
                __builtin_amdgcn_s_setprio(1);
                accO = __builtin_amdgcn_mfma_f32_32x32x16_bf16(pa.v, vb, accO, 0, 0, 0);
                __builtin_amdgcn_s_setprio(0);
            }
        }
    }

    // final l: reduce lane partials across the 4 quads sharing each qrow
    #pragma unroll
    for (int fi = 0; fi < 2; ++fi) {
        float lv = lacc[fi];
        lv += __shfl_xor(lv, 16);
        lv += __shfl_xor(lv, 32);
        if (quad == 0) Ls[wave * 32 + fi * 16 + l16] = lv;
    }
    asm volatile("s_waitcnt lgkmcnt(0)" ::: "memory");   // wave-private rows

    // epilogue: 32x32 C/D -> Att row-major [(b,t,j)][(h,cd)]
    const int cdo = qo * 16 + l16;
    #pragma unroll
    for (int g = 0; g < 4; ++g) {
        float4 lv = *(float4*)(&Ls[wave * 32 + g * 8 + q2 * 4]);
        float rl[4] = {1.f / lv.x, 1.f / lv.y, 1.f / lv.z, 1.f / lv.w};
        #pragma unroll
        for (int r = 0; r < 4; ++r) {
            int qrow = g * 8 + q2 * 4 + r;
            int trow = qt * 128 + wave * 32 + qrow;
            float v  = accO[g * 4 + r] * rl[r];
            Att[(size_t)(base0 + trow * RST + cdo)] = f2bf(v);
        }
    }
}

extern "C" void kernel_launch(void* const* d_in, const int* in_sizes, int n_in,
                              void* d_out, int out_size, void* d_ws, size_t ws_size,
                              hipStream_t stream) {
    const float* q  = (const float*)d_in[0];
    const float* kv = (const float*)d_in[1];
    const float* Wq = (const float*)d_in[2];
    const float* Wk = (const float*)d_in[3];
    const float* Wv = (const float*)d_in[4];
    const float* Wp = (const float*)d_in[5];
    const float* bp = (const float*)d_in[6];

    unsigned short* ws  = (unsigned short*)d_ws;
    unsigned short* Qp  = ws;                 // SZE
    unsigned short* Kp  = ws + SZE;           // SZE
    unsigned short* Vp  = ws + 2 * SZE;       // SZE
    unsigned short* Att = ws + 3 * SZE;       // SZE
    unsigned short* Wqb = ws + 4 * SZE;
    unsigned short* Wkb = Wqb + WSZ;
    unsigned short* Wvb = Wkb + WSZ;
    unsigned short* Wpb = Wvb + WSZ;
    float* out = (float*)d_out;

    // 0) weights-only fp32 -> bf16 prep
    prepw_kernel<<<128, 256, 0, stream>>>(Wq, Wk, Wv, Wp,
                                          Wqb, Wkb, Wvb, Wpb);
    // 1) Q/K/V projections: fp32 A inputs, fused conversion (QSCALE on z=0)
    gemm_kernel<<<dim3(272, 3), 512, 0, stream>>>(
        q, kv, Wqb, Wkb, Wvb, Qp, Kp, Vp);
    // 2) fused attention (XCD-grouped flat grid)
    attn_kernel<<<dim3(2176), 256, 0, stream>>>(Qp, Kp, Vp, Att);
    // 3) output projection + bias (fp32 out), BM=64 tail-friendly grid
    gemmo_kernel<<<dim3(544), 256, 0, stream>>>(Att, Wpb, bp, out);
}